// Round 13
// baseline (103.297 us; speedup 1.0000x reference)
//
#include <hip/hip_runtime.h>
#include <climits>

// out[i] = cond * prod_{e: idx[e]==i} factor[e];  cond = 1 - clip(t0,0,1)
// log(factor) = logC - u,  u = 0.5*((v-t2)/t1)^2,  logC = log(t0c*INV_SQRT_2PI/t1)
//
// R13 = R12 + BUGFIX: final flush now clamps to the ring window
// (se = min(c, fl+RING)) like the in-loop flush does. Records beyond the
// window were already ovf-pushed at scatter time; draining past the window
// re-read stale ring slots (duplicate records, rare-tail corruption).
//
// Structure (R12): double-buffered ring (parity = tile parity): scatter into
// ring[t&1] while flush lanes drain ring[t^1] in the SAME phase -> ONE
// barrier per tile, flush hidden under scatter. 256 buckets x 32768 slots;
// records (slot15<<17)|q17. Reduce: 256 blocks, 128KB LDS accumulator,
// packed per-half counts (cB<<8)|cA, 4 records/lane/segment pipeline.

#define INV_SQRT_2PI 0.39894246f  // 1/sqrt(2*3.14159) (matches reference)
#define SLOT_BITS 15
#define SLOTS (1 << SLOT_BITS)    // 32768 slots per bucket
#define NB 256                    // buckets (fast-path max)
#define NBLK 512                  // binning blocks
#define BTHREADS 1024             // bin block threads
#define TILE 2048                 // events per block-tile (2 per thread)
#define RING 32                   // ring slots per bucket per parity
#define QSCALE 8192.0f
#define QMASK 0x1FFFFu            // 17-bit q
#define CMASK 0xFFFFFu            // low 20 bits of scnt = count

#define LDS_BAR() do {                                        \
    asm volatile("s_waitcnt lgkmcnt(0)" ::: "memory");        \
    __builtin_amdgcn_s_barrier();                             \
} while (0)

__device__ __forceinline__ long long region_idx(int blk, int b, int nbuckets,
                                                int swzmask) {
    int bb = swzmask ? ((b + blk) & swzmask) : b;
    return (long long)blk * nbuckets + bb;
}

__device__ __forceinline__ void ovf_push(uint2* ovf, int* ovf_cnt, int ovcap,
                                         unsigned gslot, unsigned q) {
    int op = atomicAdd(ovf_cnt, 1);
    if (op < ovcap) ovf[op] = make_uint2(gslot, q);
}

__global__ __launch_bounds__(BTHREADS) void bin_kernel(
        const int* __restrict__ idx, const float* __restrict__ vals,
        const float* __restrict__ thetas,
        unsigned* __restrict__ pairs,  // [NBLK][nb][cap]; per-ring halves
        int* __restrict__ fill,        // [NBLK][nb] packed (cB<<8)|cA
        uint2* __restrict__ ovf, int* __restrict__ ovf_cnt, int ovcap,
        int n, int nbuckets, int cap_shift, int swzmask, int epb) {
    __shared__ unsigned ring[2 * RING * NB];   // [p][slot][b], 64 KB
    __shared__ int scnt[2 * NB];               // [p][b] packed (J<<20)|count

    const int tid = threadIdx.x;
    const int blk = blockIdx.x;
    const int HALF = 1 << (cap_shift - 1);
    const int HALFCH = HALF >> 4;
    long long start = (long long)blk * epb;
    long long end = start + epb;
    if (end > n) end = n;

    for (int b = tid; b < 2 * NB; b += BTHREADS) scnt[b] = 0;
    __syncthreads();

    const float t1 = thetas[1], t2 = thetas[2];
    const float t0c = fminf(fmaxf(thetas[0], 0.0f), 1.0f);
    const float inv_t1 = 1.0f / t1;

    const bool is_flusher = (tid & 63) < 16;
    const int fb = ((tid >> 6) << 4) + (tid & 63);   // flush bucket (if <16)

    // prefetch tile 0 (2 events/thread)
    int2 ck = make_int2(0, 0); float2 cv = make_float2(0.f, 0.f); int ccnt = 0;
    int2 pk2; float2 pv2;
    {
        long long te0 = start + TILE; if (te0 > end) te0 = end;
        long long base = start + (long long)tid * 2;
        if (base + 2 <= te0) {
            ck = *(const int2*)(idx + base);
            cv = *(const float2*)(vals + base);
            ccnt = 2;
        } else if (base < te0) {
            ccnt = 1; ck.x = idx[base]; cv.x = vals[base];
        }
    }

    int t = 0;
    for (long long ts = start; ts < end; ts += TILE, ++t) {
        const int p = t & 1, q = p ^ 1;

        // ---- prefetch next tile ----
        int ncnt = 0;
        long long tsn = ts + TILE;
        if (tsn < end) {
            long long ten = tsn + TILE; if (ten > end) ten = end;
            long long base = tsn + (long long)tid * 2;
            if (base + 2 <= ten) {
                pk2 = *(const int2*)(idx + base);
                pv2 = *(const float2*)(vals + base);
                ncnt = 2;
            } else if (base < ten) {
                ncnt = 1; pk2.x = idx[base]; pv2.x = vals[base];
            }
        }

        // ---- scatter 2 events into ring[p] ----
        int   kk[2] = {ck.x, ck.y};
        float vv[2] = {cv.x, cv.y};
        #pragma unroll
        for (int j = 0; j < 2; ++j) {
            if (j >= ccnt) continue;
            unsigned uk = (unsigned)kk[j];
            int b = (int)(uk >> SLOT_BITS);
            if (b >= nbuckets) continue;
            float z = (vv[j] - t2) * inv_t1;
            float u = 0.5f * z * z;
            unsigned qq = __float2uint_rn(fminf(u * QSCALE, (float)QMASK));
            unsigned rec = ((uk & (SLOTS - 1)) << 17) | qq;
            int ret = atomicAdd(&scnt[p * NB + b], 1);
            int pos = ret & CMASK;
            int fl = (ret >> 20) << 4;
            if (pos - fl < RING)
                ring[(p * RING + (pos & (RING - 1))) * NB + b] = rec;
            else
                ovf_push(ovf, ovf_cnt, ovcap, uk, qq);
        }

        // ---- concurrently flush ring[q] (previous tile, post-barrier) ----
        if (is_flusher && fb < nbuckets) {
            int pk = scnt[q * NB + fb];
            int c = pk & CMASK;
            int J = pk >> 20;
            int fl = J << 4;
            int se = c < fl + RING ? c : fl + RING;
            int na = se - fl;
            bool upd = (se != c);
            while (na >= 16) {
                int H = (J & 1) << 4;
                unsigned tmp[16];
                #pragma unroll
                for (int i = 0; i < 16; ++i)
                    tmp[i] = ring[(q * RING + H + i) * NB + fb];
                if (J < HALFCH) {
                    uint4* d4 = (uint4*)(pairs +
                        (region_idx(blk, fb, nbuckets, swzmask) << cap_shift)
                        + q * HALF + (J << 4));
                    const uint4* t4 = (const uint4*)tmp;
                    d4[0]=t4[0]; d4[1]=t4[1]; d4[2]=t4[2]; d4[3]=t4[3];
                } else {
                    for (int i = 0; i < 16; ++i)
                        ovf_push(ovf, ovf_cnt, ovcap,
                                 ((unsigned)fb << SLOT_BITS) | (tmp[i] >> 17),
                                 tmp[i] & QMASK);
                }
                ++J; fl += 16; na -= 16; upd = true;
            }
            if (upd) scnt[q * NB + fb] = (J << 20) | se;
        }

        LDS_BAR();   // one barrier per tile
        ck = pk2; cv = pv2; ccnt = ncnt;
    }

    // ---- final flush: both parities, clamped to ring window (BUGFIX) ----
    if (is_flusher && fb < nbuckets) {
        int vc[2];
        #pragma unroll
        for (int pp = 0; pp < 2; ++pp) {
            int pk = scnt[pp * NB + fb];
            int c = pk & CMASK;
            int J = pk >> 20;
            int fl = J << 4;
            int se = c < fl + RING ? c : fl + RING;   // spilled tail already in ovf
            // remaining full chunks (within window)
            while (se - fl >= 16) {
                unsigned tmp[16];
                #pragma unroll
                for (int i = 0; i < 16; ++i)
                    tmp[i] = ring[(pp * RING + ((fl + i) & (RING - 1))) * NB + fb];
                if (J < HALFCH) {
                    uint4* d4 = (uint4*)(pairs +
                        (region_idx(blk, fb, nbuckets, swzmask) << cap_shift)
                        + pp * HALF + (J << 4));
                    const uint4* t4 = (const uint4*)tmp;
                    d4[0]=t4[0]; d4[1]=t4[1]; d4[2]=t4[2]; d4[3]=t4[3];
                    ++J;
                } else {
                    for (int i = 0; i < 16; ++i)
                        ovf_push(ovf, ovf_cnt, ovcap,
                                 ((unsigned)fb << SLOT_BITS) | (tmp[i] >> 17),
                                 tmp[i] & QMASK);
                }
                fl += 16;
            }
            int r = se - fl;         // 0..15 within window
            int rw = 0;
            if (r > 0) {
                if (J < HALFCH) {
                    unsigned tmp[16];
                    #pragma unroll
                    for (int i = 0; i < 16; ++i)
                        tmp[i] = ring[(pp * RING + ((fl + i) & (RING - 1))) * NB + fb];
                    uint4* d4 = (uint4*)(pairs +
                        (region_idx(blk, fb, nbuckets, swzmask) << cap_shift)
                        + pp * HALF + (J << 4));
                    const uint4* t4 = (const uint4*)tmp;
                    d4[0]=t4[0]; d4[1]=t4[1]; d4[2]=t4[2]; d4[3]=t4[3];
                    rw = r;
                } else {
                    for (int i = 0; i < r; ++i) {
                        unsigned rr = ring[(pp * RING + ((fl + i) & (RING - 1))) * NB + fb];
                        ovf_push(ovf, ovf_cnt, ovcap,
                                 ((unsigned)fb << SLOT_BITS) | (rr >> 17),
                                 rr & QMASK);
                    }
                }
            }
            vc[pp] = (J << 4) + rw;
        }
        fill[region_idx(blk, fb, nbuckets, swzmask)] = (vc[1] << 8) | vc[0];
    }
}

__global__ __launch_bounds__(1024) void reduce_kernel(
        const unsigned* __restrict__ pairs, const int* __restrict__ fill,
        const uint2* __restrict__ ovf, const int* __restrict__ ovf_cnt, int ovcap,
        const float* __restrict__ thetas, float* __restrict__ out,
        long long n_out, int nbuckets, int swzmask) {
    __shared__ unsigned accu[SLOTS];   // 128 KB packed: count<<25 | sum_q
    const int tid = threadIdx.x;
    const int b = blockIdx.x;

    for (int s = tid; s < SLOTS; s += 1024) accu[s] = 0u;
    __syncthreads();

    const int wave = tid >> 6, lane = tid & 63;
    const int SEGS = NBLK / 16;   // 32 segments per wave

    // lane i holds packed counts of segment (wave + i*16)
    int sl = wave + (lane & 31) * 16;
    int cntv = fill[region_idx(sl, b, nbuckets, swzmask)];

    // pipelined segment stream: 4 records/lane/segment (cap = 256)
    const unsigned* pc = pairs + (region_idx(wave, b, nbuckets, swzmask) << 8);
    unsigned a0 = pc[lane], a1 = pc[64 + lane];
    unsigned a2 = pc[128 + lane], a3 = pc[192 + lane];

    for (int i = 0; i < SEGS; ++i) {
        unsigned n0 = 0, n1 = 0, n2 = 0, n3 = 0;
        if (i < SEGS - 1) {
            int sn = wave + (i + 1) * 16;
            const unsigned* pn = pairs +
                (region_idx(sn, b, nbuckets, swzmask) << 8);
            n0 = pn[lane]; n1 = pn[64 + lane];
            n2 = pn[128 + lane]; n3 = pn[192 + lane];
        }
        int cpk = __builtin_amdgcn_readlane(cntv, i);
        int cA = cpk & 0xFF, cB = (cpk >> 8) & 0xFF;
        if (lane < cA)      atomicAdd(&accu[a0 >> 17], (1u << 25) + (a0 & QMASK));
        if (64 + lane < cA) atomicAdd(&accu[a1 >> 17], (1u << 25) + (a1 & QMASK));
        if (lane < cB)      atomicAdd(&accu[a2 >> 17], (1u << 25) + (a2 & QMASK));
        if (64 + lane < cB) atomicAdd(&accu[a3 >> 17], (1u << 25) + (a3 & QMASK));
        a0 = n0; a1 = n1; a2 = n2; a3 = n3;
    }
    __syncthreads();

    int no = *ovf_cnt; if (no > ovcap) no = ovcap;
    for (int i = tid; i < no; i += 1024) {
        uint2 e = ovf[i];
        if ((int)(e.x >> SLOT_BITS) == b)
            atomicAdd(&accu[e.x & (SLOTS - 1)], (1u << 25) + e.y);
    }
    __syncthreads();

    const float t1 = thetas[1];
    const float t0c = fminf(fmaxf(thetas[0], 0.0f), 1.0f);
    const float logC = logf(t0c * INV_SQRT_2PI / t1);
    const float cond = 1.0f - t0c;
    long long obase = (long long)b << SLOT_BITS;
    for (int ss = tid; ss < SLOTS; ss += 1024) {
        long long o = obase + ss;
        if (o < n_out) {
            unsigned av = accu[ss];
            float v = (float)(av >> 25) * logC
                    - (float)(av & 0x1FFFFFFu) * (1.0f / QSCALE);
            out[o] = cond * expf(v);
        }
    }
}

// ---- fallback path: direct global atomics (R1) ----
__global__ void init_zero_kernel(float* __restrict__ out, int n) {
    int i = blockIdx.x * blockDim.x + threadIdx.x;
    int stride = gridDim.x * blockDim.x;
    for (; i < n; i += stride) out[i] = 0.0f;
}
__global__ void scatter_log_kernel(const int* __restrict__ idx,
                                   const float* __restrict__ vals,
                                   const float* __restrict__ thetas,
                                   float* __restrict__ acc, int n) {
    float t1 = thetas[1], t2 = thetas[2];
    float t0c = fminf(fmaxf(thetas[0], 0.0f), 1.0f);
    float logC = logf(t0c * INV_SQRT_2PI / t1);
    float inv_t1 = 1.0f / t1;
    int i = blockIdx.x * blockDim.x + threadIdx.x;
    int stride = gridDim.x * blockDim.x;
    for (; i < n; i += stride) {
        float z = (vals[i] - t2) * inv_t1;
        atomicAdd(&acc[idx[i]], fmaf(-0.5f * z, z, logC));
    }
}
__global__ void finalize_kernel(float* __restrict__ out,
                                const float* __restrict__ thetas, int n) {
    float t0c = fminf(fmaxf(thetas[0], 0.0f), 1.0f);
    float cond = 1.0f - t0c;
    int i = blockIdx.x * blockDim.x + threadIdx.x;
    int stride = gridDim.x * blockDim.x;
    for (; i < n; i += stride) out[i] = cond * expf(out[i]);
}

extern "C" void kernel_launch(void* const* d_in, const int* in_sizes, int n_in,
                              void* d_out, int out_size, void* d_ws, size_t ws_size,
                              hipStream_t stream) {
    // inputs: [0]=batch (scalar), [1]=idx (int32), [2]=vals (f32), [3]=thetas (f32 x3)
    const int*   idx    = (const int*)d_in[1];
    const float* vals   = (const float*)d_in[2];
    const float* thetas = (const float*)d_in[3];
    float*       out    = (float*)d_out;

    int n_events = in_sizes[1];
    long long n_out = out_size;
    int nbuckets = (int)((n_out + SLOTS - 1) >> SLOT_BITS);

    // geometry
    long long tiles_total = ((long long)n_events + TILE - 1) / TILE;
    long long tpb = (tiles_total + NBLK - 1) / NBLK;
    int epb = (int)(tpb * TILE);
    long long avg = nbuckets > 0 ? (epb + nbuckets - 1) / nbuckets : 1;
    long long want = avg + avg / 2 + 64;
    int cap_shift = 6;
    while ((1LL << cap_shift) < want && cap_shift < 20) ++cap_shift;
    long long cappb = 1LL << cap_shift;
    int swzmask = (nbuckets > 0 && (nbuckets & (nbuckets - 1)) == 0)
                  ? nbuckets - 1 : 0;

    size_t pairs_b = (size_t)NBLK * nbuckets * cappb * 4;
    size_t fill_b  = (size_t)NBLK * nbuckets * 4;
    size_t head    = pairs_b + fill_b + 64;
    // reduce assumes cap = 256 (4 records/lane); gate on it
    bool fast = (nbuckets > 0) && (nbuckets <= NB) && (n_events > 0) &&
                (cap_shift == 8) && (ws_size >= head + 64 * 1024);

    if (fast) {
        unsigned* pairs = (unsigned*)d_ws;
        int* fill = (int*)((char*)d_ws + pairs_b);
        int* ovf_cnt = (int*)((char*)d_ws + pairs_b + fill_b);
        uint2* ovf = (uint2*)((char*)d_ws + head);
        long long ovcap_ll = (long long)((ws_size - head) / 8);
        int ovcap = (int)(ovcap_ll > 4194304 ? 4194304 : ovcap_ll);

        hipMemsetAsync(ovf_cnt, 0, sizeof(int), stream);
        bin_kernel<<<NBLK, BTHREADS, 0, stream>>>(idx, vals, thetas, pairs, fill,
                                                  ovf, ovf_cnt, ovcap,
                                                  n_events, nbuckets, cap_shift,
                                                  swzmask, epb);
        reduce_kernel<<<nbuckets, 1024, 0, stream>>>(pairs, fill, ovf, ovf_cnt,
                                                     ovcap, thetas, out,
                                                     n_out, nbuckets, swzmask);
    } else {
        const int BLOCK = 256;
        int grid_out = min((int)((n_out + BLOCK - 1) / BLOCK), 2048);
        int grid_ev  = min((n_events + BLOCK - 1) / BLOCK, 2048);
        init_zero_kernel<<<grid_out, BLOCK, 0, stream>>>(out, (int)n_out);
        scatter_log_kernel<<<grid_ev, BLOCK, 0, stream>>>(idx, vals, thetas, out, n_events);
        finalize_kernel<<<grid_out, BLOCK, 0, stream>>>(out, thetas, (int)n_out);
    }
}